// Round 1
// baseline (409.380 us; speedup 1.0000x reference)
//
#include <hip/hip_runtime.h>

// TemporalDilatedAttention on gfx950 — round 1 (correctness-first MFMA impl)
// Pipeline: weight transpose+cvt(f16) -> x/hist cvt -> Q gemm (scaled) ->
// fused K/V gemm (V stored transposed) -> flash attention partials ->
// combine (softmax over dilation weights) -> out gemm -> residual+layernorm.

#define DD    1024
#define NH    4
#define HDIM  256
#define NB    256
#define TALL  16384

typedef _Float16 half8  __attribute__((ext_vector_type(8)));
typedef _Float16 half4v __attribute__((ext_vector_type(4)));
typedef float    floatx4 __attribute__((ext_vector_type(4)));

// ---------------- workspace layout (bytes) ----------------
// needs ~137 MB of d_ws
static const size_t OFF_WQT = 0;                       // 1024*1024*2
static const size_t OFF_WKT = 2097152;
static const size_t OFF_WVT = 4194304;
static const size_t OFF_WOT = 6291456;
static const size_t OFF_XB  = 8388608;                 // 256*1024*2
static const size_t OFF_QS  = 8912896;                 // 256*1024*2 (scaled Q, f16)
static const size_t OFF_HB  = 16777216;                // 16384*1024*2
static const size_t OFF_KB  = 50331648;                // 16384*1024*2
static const size_t OFF_VT  = 83886080;                // 1024*16384*2 (V transposed)
static const size_t OFF_OP  = 117440512;               // 23*4*256*256*4 O partials
static const size_t OFF_MP  = 141557760;               // 23*4*256*4
static const size_t OFF_LP  = 141651968;               // 23*4*256*4
static const size_t OFF_CB  = 141746176;               // 256*1024*2 combined f16
static const size_t OFF_CP  = 142270464;               // 256*1024*4 out-proj f32

// ---------------- weight transpose + convert ----------------
// WT[n][k] = (f16) W[k][n]; blockIdx.z selects which weight
__global__ void wtrans_kernel(const float* __restrict__ W0, const float* __restrict__ W1,
                              const float* __restrict__ W2, const float* __restrict__ W3,
                              _Float16* __restrict__ T0, _Float16* __restrict__ T1,
                              _Float16* __restrict__ T2, _Float16* __restrict__ T3) {
  const float* W; _Float16* T;
  switch (blockIdx.z) {
    case 0: W = W0; T = T0; break;
    case 1: W = W1; T = T1; break;
    case 2: W = W2; T = T2; break;
    default: W = W3; T = T3; break;
  }
  __shared__ float tile[32][33];
  int tx = threadIdx.x & 31, ty = threadIdx.x >> 5;   // ty 0..7
  int k0 = blockIdx.x * 32, n0 = blockIdx.y * 32;
#pragma unroll
  for (int i = 0; i < 4; i++) {
    int r = ty + i * 8;
    tile[r][tx] = W[(size_t)(k0 + r) * DD + n0 + tx];
  }
  __syncthreads();
#pragma unroll
  for (int i = 0; i < 4; i++) {
    int r = ty + i * 8;
    T[(size_t)(n0 + r) * DD + k0 + tx] = (_Float16)tile[tx][r];
  }
}

// ---------------- fp32 -> f16 convert (vectorized) ----------------
__global__ void cvt_kernel(const float* __restrict__ in, _Float16* __restrict__ out, int n4) {
  int i = blockIdx.x * 256 + threadIdx.x;
  if (i >= n4) return;
  float4 v = ((const float4*)in)[i];
  half4v h = {(_Float16)v.x, (_Float16)v.y, (_Float16)v.z, (_Float16)v.w};
  *(half4v*)(out + 4 * (size_t)i) = h;
}

// ---------------- fused K/V projection GEMM ----------------
// A: M x 1024 f16 (hist), WkT/WvT: 1024x1024 f16 transposed weights.
// K[t][n] = A@Wk + bk ; Vt[n][t] = A@Wv + bv (transposed store).
// grid: (N/128=8, M/128), block 256 (4 waves, 2x2 of 64x64)
__launch_bounds__(256, 2)
__global__ void gemm_kv_kernel(const _Float16* __restrict__ A,
                               const _Float16* __restrict__ WkT, const _Float16* __restrict__ WvT,
                               const float* __restrict__ bk, const float* __restrict__ bv,
                               _Float16* __restrict__ K, _Float16* __restrict__ Vt) {
  __shared__ _Float16 As[128][40];
  __shared__ _Float16 Bk[128][40];
  __shared__ _Float16 Bv[128][40];
  int tid = threadIdx.x;
  int lane = tid & 63, w = tid >> 6;
  int l15 = lane & 15, quad = lane >> 4;
  int wm = (w >> 1) * 64, wn = (w & 1) * 64;
  int m0 = blockIdx.y * 128, n0 = blockIdx.x * 128;
  floatx4 accK[4][4], accV[4][4];
  floatx4 zero = {0.f, 0.f, 0.f, 0.f};
#pragma unroll
  for (int a = 0; a < 4; a++)
#pragma unroll
    for (int b = 0; b < 4; b++) { accK[a][b] = zero; accV[a][b] = zero; }
  int sr = tid >> 2;    // 0..63 row group
  int sc = tid & 3;     // 16B chunk in a 64B row
  for (int kt = 0; kt < 1024; kt += 32) {
    __syncthreads();
#pragma unroll
    for (int it = 0; it < 2; it++) {
      int r = sr + it * 64;
      *(uint4*)&As[r][sc * 8] = *(const uint4*)&A[(size_t)(m0 + r) * 1024 + kt + sc * 8];
      *(uint4*)&Bk[r][sc * 8] = *(const uint4*)&WkT[(size_t)(n0 + r) * 1024 + kt + sc * 8];
      *(uint4*)&Bv[r][sc * 8] = *(const uint4*)&WvT[(size_t)(n0 + r) * 1024 + kt + sc * 8];
    }
    __syncthreads();
    half8 a[4];
#pragma unroll
    for (int mi = 0; mi < 4; mi++) a[mi] = *(const half8*)&As[wm + mi * 16 + l15][quad * 8];
#pragma unroll
    for (int ni = 0; ni < 4; ni++) {
      half8 bk8 = *(const half8*)&Bk[wn + ni * 16 + l15][quad * 8];
      half8 bv8 = *(const half8*)&Bv[wn + ni * 16 + l15][quad * 8];
#pragma unroll
      for (int mi = 0; mi < 4; mi++) {
        accK[mi][ni] = __builtin_amdgcn_mfma_f32_16x16x32_f16(a[mi], bk8, accK[mi][ni], 0, 0, 0);
        accV[mi][ni] = __builtin_amdgcn_mfma_f32_16x16x32_f16(a[mi], bv8, accV[mi][ni], 0, 0, 0);
      }
    }
  }
#pragma unroll
  for (int mi = 0; mi < 4; mi++)
#pragma unroll
    for (int ni = 0; ni < 4; ni++) {
      int col = n0 + wn + ni * 16 + l15;
      float bkv = bk[col], bvv = bv[col];
#pragma unroll
      for (int r = 0; r < 4; r++) {
        int row = m0 + wm + mi * 16 + quad * 4 + r;
        K[(size_t)row * 1024 + col] = (_Float16)(accK[mi][ni][r] + bkv);
        Vt[(size_t)col * TALL + row] = (_Float16)(accV[mi][ni][r] + bvv);
      }
    }
}

// ---------------- single-output GEMM (Q proj / out proj) ----------------
template <bool OUTF32>
__launch_bounds__(256, 2)
__global__ void gemm_single_kernel(const _Float16* __restrict__ A, const _Float16* __restrict__ WT,
                                   const float* __restrict__ bias, void* __restrict__ Cout,
                                   float scale) {
  __shared__ _Float16 As[128][40];
  __shared__ _Float16 Bs[128][40];
  int tid = threadIdx.x;
  int lane = tid & 63, w = tid >> 6;
  int l15 = lane & 15, quad = lane >> 4;
  int wm = (w >> 1) * 64, wn = (w & 1) * 64;
  int m0 = blockIdx.y * 128, n0 = blockIdx.x * 128;
  floatx4 acc[4][4];
  floatx4 zero = {0.f, 0.f, 0.f, 0.f};
#pragma unroll
  for (int a = 0; a < 4; a++)
#pragma unroll
    for (int b = 0; b < 4; b++) acc[a][b] = zero;
  int sr = tid >> 2, sc = tid & 3;
  for (int kt = 0; kt < 1024; kt += 32) {
    __syncthreads();
#pragma unroll
    for (int it = 0; it < 2; it++) {
      int r = sr + it * 64;
      *(uint4*)&As[r][sc * 8] = *(const uint4*)&A[(size_t)(m0 + r) * 1024 + kt + sc * 8];
      *(uint4*)&Bs[r][sc * 8] = *(const uint4*)&WT[(size_t)(n0 + r) * 1024 + kt + sc * 8];
    }
    __syncthreads();
    half8 a[4];
#pragma unroll
    for (int mi = 0; mi < 4; mi++) a[mi] = *(const half8*)&As[wm + mi * 16 + l15][quad * 8];
#pragma unroll
    for (int ni = 0; ni < 4; ni++) {
      half8 b8 = *(const half8*)&Bs[wn + ni * 16 + l15][quad * 8];
#pragma unroll
      for (int mi = 0; mi < 4; mi++)
        acc[mi][ni] = __builtin_amdgcn_mfma_f32_16x16x32_f16(a[mi], b8, acc[mi][ni], 0, 0, 0);
    }
  }
#pragma unroll
  for (int mi = 0; mi < 4; mi++)
#pragma unroll
    for (int ni = 0; ni < 4; ni++) {
      int col = n0 + wn + ni * 16 + l15;
      float bv = bias[col];
#pragma unroll
      for (int r = 0; r < 4; r++) {
        int row = m0 + wm + mi * 16 + quad * 4 + r;
        float v = (acc[mi][ni][r] + bv) * scale;
        if (OUTF32) ((float*)Cout)[(size_t)row * 1024 + col] = v;
        else ((_Float16*)Cout)[(size_t)row * 1024 + col] = (_Float16)v;
      }
    }
}

// ---------------- flash attention partials ----------------
// grid: (23 segs, 4 heads, 4 qtiles of 64), block 256 (4 waves x 16 q-rows)
// seg = 1024 keys of the dilation's frame list; chunks of 32 keys map to
// 32 contiguous rows of K (t = frame*256 + batch).
__launch_bounds__(256, 2)
__global__ void attn_kernel(const _Float16* __restrict__ Q, const _Float16* __restrict__ K,
                            const _Float16* __restrict__ Vt, float* __restrict__ Opart,
                            float* __restrict__ mpart, float* __restrict__ lpart) {
  int s = blockIdx.x, h = blockIdx.y, qt = blockIdx.z;
  int d, sl;
  if (s < 16)      { d = 1;  sl = s; }
  else if (s < 20) { d = 4;  sl = s - 16; }
  else if (s < 22) { d = 8;  sl = s - 20; }
  else             { d = 16; sl = s - 22; }
  __shared__ _Float16 Kc[32][264];   // 32 keys x 256 feat (+8 pad)
  __shared__ _Float16 Vc[256][40];   // 256 feat x 32 keys (+8 pad)
  __shared__ _Float16 Pl[4][16][40]; // per-wave P tile 16x32 (+8 pad)
  int tid = threadIdx.x, lane = tid & 63, w = tid >> 6;
  int l15 = lane & 15, quad = lane >> 4;
  int qrow = qt * 64 + w * 16 + l15;
  half8 qf[8];
#pragma unroll
  for (int ks = 0; ks < 8; ks++)
    qf[ks] = *(const half8*)&Q[(size_t)qrow * 1024 + h * 256 + ks * 32 + quad * 8];
  float mrun[4], lrun[4];
  floatx4 accO[16];
  floatx4 zero = {0.f, 0.f, 0.f, 0.f};
#pragma unroll
  for (int r = 0; r < 4; r++) { mrun[r] = -1e30f; lrun[r] = 0.f; }
#pragma unroll
  for (int nt = 0; nt < 16; nt++) accO[nt] = zero;
  int j0 = sl * 1024;
  for (int c = 0; c < 32; c++) {
    int j = j0 + c * 32;
    int fi = j >> 8;       // index in the dilation's selected-frame list
    int b0 = j & 255;
    size_t trow0 = (size_t)(fi * d) * 256 + b0;
    __syncthreads();
#pragma unroll
    for (int p = 0; p < 4; p++) {
      int slot = tid + p * 256;
      int kr = slot >> 5, kc = slot & 31;
      *(uint4*)&Kc[kr][kc * 8] = *(const uint4*)&K[(trow0 + kr) * 1024 + h * 256 + kc * 8];
      int vf = slot >> 2, vc = slot & 3;
      *(uint4*)&Vc[vf][vc * 8] = *(const uint4*)&Vt[(size_t)(h * 256 + vf) * TALL + trow0 + vc * 8];
    }
    __syncthreads();
    floatx4 sc2[2] = {zero, zero};
#pragma unroll
    for (int ks = 0; ks < 8; ks++) {
#pragma unroll
      for (int tt = 0; tt < 2; tt++) {
        half8 kf = *(const half8*)&Kc[tt * 16 + l15][ks * 32 + quad * 8];
        sc2[tt] = __builtin_amdgcn_mfma_f32_16x16x32_f16(qf[ks], kf, sc2[tt], 0, 0, 0);
      }
    }
    float e0[4], e1[4], alpha[4];
#pragma unroll
    for (int r = 0; r < 4; r++) {
      float mx = fmaxf(sc2[0][r], sc2[1][r]);
#pragma unroll
      for (int off = 8; off >= 1; off >>= 1) mx = fmaxf(mx, __shfl_xor(mx, off, 64));
      float mnew = fmaxf(mrun[r], mx);
      e0[r] = __expf(sc2[0][r] - mnew);
      e1[r] = __expf(sc2[1][r] - mnew);
      float rs = e0[r] + e1[r];
#pragma unroll
      for (int off = 8; off >= 1; off >>= 1) rs += __shfl_xor(rs, off, 64);
      alpha[r] = __expf(mrun[r] - mnew);
      lrun[r] = lrun[r] * alpha[r] + rs;
      mrun[r] = mnew;
    }
#pragma unroll
    for (int nt = 0; nt < 16; nt++)
#pragma unroll
      for (int r = 0; r < 4; r++) accO[nt][r] *= alpha[r];
#pragma unroll
    for (int r = 0; r < 4; r++) {
      Pl[w][quad * 4 + r][l15] = (_Float16)e0[r];
      Pl[w][quad * 4 + r][16 + l15] = (_Float16)e1[r];
    }
    // same-wave LDS write->read: in-order DS pipe, compiler inserts lgkmcnt
    half8 pf = *(const half8*)&Pl[w][l15][quad * 8];
#pragma unroll
    for (int nt = 0; nt < 16; nt++) {
      half8 vf8 = *(const half8*)&Vc[nt * 16 + l15][quad * 8];
      accO[nt] = __builtin_amdgcn_mfma_f32_16x16x32_f16(pf, vf8, accO[nt], 0, 0, 0);
    }
  }
  size_t base = ((size_t)(s * 4 + h) * 256 + qt * 64 + w * 16);
#pragma unroll
  for (int nt = 0; nt < 16; nt++)
#pragma unroll
    for (int r = 0; r < 4; r++)
      Opart[(base + quad * 4 + r) * 256 + nt * 16 + l15] = accO[nt][r];
  if (l15 == 0) {
#pragma unroll
    for (int r = 0; r < 4; r++) {
      mpart[base + quad * 4 + r] = mrun[r];
      lpart[base + quad * 4 + r] = lrun[r];
    }
  }
}

// ---------------- combine partials + dilation-weight softmax ----------------
// grid (4 heads, 256 batch), block 256 (feature within head)
__global__ void combine_kernel(const float* __restrict__ Opart, const float* __restrict__ mpart,
                               const float* __restrict__ lpart, const float* __restrict__ dil_w,
                               _Float16* __restrict__ comb) {
  int h = blockIdx.x, b = blockIdx.y, n = threadIdx.x;
  float w0 = dil_w[0], w1 = dil_w[1], w2 = dil_w[2], w3 = dil_w[3];
  float wmx = fmaxf(fmaxf(w0, w1), fmaxf(w2, w3));
  float ww[4] = {__expf(w0 - wmx), __expf(w1 - wmx), __expf(w2 - wmx), __expf(w3 - wmx)};
  float wsum = ww[0] + ww[1] + ww[2] + ww[3];
  const int SEGB[4] = {0, 16, 20, 22};
  const int SEGC[4] = {16, 4, 2, 1};
  float out = 0.f;
  for (int di = 0; di < 4; di++) {
    float mstar = -1e30f;
    for (int si = 0; si < SEGC[di]; si++) {
      int sg = SEGB[di] + si;
      mstar = fmaxf(mstar, mpart[(size_t)(sg * 4 + h) * 256 + b]);
    }
    float den = 0.f, num = 0.f;
    for (int si = 0; si < SEGC[di]; si++) {
      int sg = SEGB[di] + si;
      size_t idx = (size_t)(sg * 4 + h) * 256 + b;
      float f = __expf(mpart[idx] - mstar);
      den += lpart[idx] * f;
      num += f * Opart[idx * 256 + n];
    }
    out += (ww[di] / wsum) * (num / den);
  }
  comb[(size_t)b * 1024 + h * 256 + n] = (_Float16)out;
}

// ---------------- residual + layernorm ----------------
// cproj already contains combined@Wo + bo
__global__ void ln_kernel(const float* __restrict__ x, const float* __restrict__ cproj,
                          const float* __restrict__ gamma, const float* __restrict__ beta,
                          float* __restrict__ out) {
  int b = blockIdx.x, t = threadIdx.x;
  __shared__ float red[8];
  float y[4];
  float sum = 0.f, sq = 0.f;
#pragma unroll
  for (int i = 0; i < 4; i++) {
    int j = t + i * 256;
    y[i] = x[(size_t)b * 1024 + j] + cproj[(size_t)b * 1024 + j];
    sum += y[i];
    sq += y[i] * y[i];
  }
#pragma unroll
  for (int off = 1; off < 64; off <<= 1) {
    sum += __shfl_xor(sum, off, 64);
    sq += __shfl_xor(sq, off, 64);
  }
  int w = t >> 6, lane = t & 63;
  if (lane == 0) { red[w] = sum; red[4 + w] = sq; }
  __syncthreads();
  sum = red[0] + red[1] + red[2] + red[3];
  sq = red[4] + red[5] + red[6] + red[7];
  float mu = sum * (1.f / 1024.f);
  float var = sq * (1.f / 1024.f) - mu * mu;
  float inv = rsqrtf(var + 1e-5f);
#pragma unroll
  for (int i = 0; i < 4; i++) {
    int j = t + i * 256;
    out[(size_t)b * 1024 + j] = (y[i] - mu) * inv * gamma[j] + beta[j];
  }
}

// ---------------- host launch ----------------
extern "C" void kernel_launch(void* const* d_in, const int* in_sizes, int n_in,
                              void* d_out, int out_size, void* d_ws, size_t ws_size,
                              hipStream_t stream) {
  const float* x     = (const float*)d_in[0];
  const float* hist  = (const float*)d_in[1];
  const float* Wq    = (const float*)d_in[2];
  const float* bq    = (const float*)d_in[3];
  const float* Wk    = (const float*)d_in[4];
  const float* bk    = (const float*)d_in[5];
  const float* Wv    = (const float*)d_in[6];
  const float* bv    = (const float*)d_in[7];
  const float* Wo    = (const float*)d_in[8];
  const float* bo    = (const float*)d_in[9];
  const float* dil_w = (const float*)d_in[10];
  const float* gamma = (const float*)d_in[11];
  const float* beta  = (const float*)d_in[12];
  char* ws = (char*)d_ws;

  _Float16* WqT   = (_Float16*)(ws + OFF_WQT);
  _Float16* WkT   = (_Float16*)(ws + OFF_WKT);
  _Float16* WvT   = (_Float16*)(ws + OFF_WVT);
  _Float16* WoT   = (_Float16*)(ws + OFF_WOT);
  _Float16* xb    = (_Float16*)(ws + OFF_XB);
  _Float16* Qs    = (_Float16*)(ws + OFF_QS);
  _Float16* histb = (_Float16*)(ws + OFF_HB);
  _Float16* Kb    = (_Float16*)(ws + OFF_KB);
  _Float16* Vtb   = (_Float16*)(ws + OFF_VT);
  float* Opart    = (float*)(ws + OFF_OP);
  float* mpart    = (float*)(ws + OFF_MP);
  float* lpart    = (float*)(ws + OFF_LP);
  _Float16* comb  = (_Float16*)(ws + OFF_CB);
  float* cproj    = (float*)(ws + OFF_CP);

  // 1) weights -> transposed f16
  wtrans_kernel<<<dim3(32, 32, 4), 256, 0, stream>>>(Wq, Wk, Wv, Wo, WqT, WkT, WvT, WoT);
  // 2) inputs -> f16
  cvt_kernel<<<dim3(16384), 256, 0, stream>>>(hist, histb, 16777216 / 4);
  cvt_kernel<<<dim3(256), 256, 0, stream>>>(x, xb, 262144 / 4);
  // 3) Q projection (scale 1/sqrt(HD) folded in)
  gemm_single_kernel<false><<<dim3(8, 2), 256, 0, stream>>>(xb, WqT, bq, (void*)Qs, 0.0625f);
  // 4) fused K / V(t) projection
  gemm_kv_kernel<<<dim3(8, 128), 256, 0, stream>>>(histb, WkT, WvT, bk, bv, Kb, Vtb);
  // 5) attention partials
  attn_kernel<<<dim3(23, 4, 4), 256, 0, stream>>>(Qs, Kb, Vtb, Opart, mpart, lpart);
  // 6) combine across segments & dilations
  combine_kernel<<<dim3(4, 256), 256, 0, stream>>>(Opart, mpart, lpart, dil_w, comb);
  // 7) output projection (+bo)
  gemm_single_kernel<true><<<dim3(8, 2), 256, 0, stream>>>(comb, WoT, bo, (void*)cproj, 1.0f);
  // 8) residual + layernorm
  ln_kernel<<<dim3(256), 256, 0, stream>>>(x, cproj, gamma, beta, (float*)d_out);
}

// Round 2
// 338.377 us; speedup vs baseline: 1.2098x; 1.2098x over previous
//
#include <hip/hip_runtime.h>

// TemporalDilatedAttention on gfx950 — round 2
// Changes vs R1: (1) attention GEMM-ified: S = Q@K^T once (global-max softmax
// lets all dilations share exp terms; merged per-key weight = e_j * c_frame),
// single PV GEMM with split-K. (2) all GEMMs use global_load_lds width-16
// staging (m97 structure, unpadded [128][32] LDS tiles).

#define DD    1024
#define TALL  16384

typedef _Float16 half8  __attribute__((ext_vector_type(8)));
typedef _Float16 half4v __attribute__((ext_vector_type(4)));
typedef float    floatx4 __attribute__((ext_vector_type(4)));
typedef unsigned int u32;

// ---------------- workspace layout (bytes) ----------------
static const size_t OFF_WQT = 0;          // 2 MB
static const size_t OFF_WKT = 2097152;
static const size_t OFF_WVT = 4194304;
static const size_t OFF_WOT = 6291456;
static const size_t OFF_XB  = 8388608;    // 0.5 MB
static const size_t OFF_QS  = 8912896;    // 0.5 MB
static const size_t OFF_HB  = 16777216;   // 32 MB hist f16; ALIASED by S after KV gemm
static const size_t OFF_S   = OFF_HB;     // S/P: 4 heads x 256 q x 16384 keys f16 = 32 MB
static const size_t OFF_KB  = 50331648;   // 32 MB
static const size_t OFF_VT  = 83886080;   // 32 MB (V transposed [feat][t])
static const size_t OFF_PART= 117440512;  // 16 x 256 x 1024 f32 = 16 MB
static const size_t OFF_MT  = 134217728;  // 1024 f32
static const size_t OFF_CT  = 134221824;  // 1024 x 64 f32 = 256 KB
static const size_t OFF_CB  = 134483968;  // comb 256x1024 f16 = 0.5 MB
static const size_t OFF_CP  = 135008256;  // cproj 256x1024 f32 = 1 MB

// ---------------- async global->LDS, 16B per lane ----------------
__device__ __forceinline__ void gl_lds16(const void* g, void* l) {
  __builtin_amdgcn_global_load_lds((const __attribute__((address_space(1))) u32*)g,
                                   (__attribute__((address_space(3))) u32*)l, 16, 0, 0);
}

// ---------------- weight transpose + convert ----------------
__global__ void wtrans_kernel(const float* __restrict__ W0, const float* __restrict__ W1,
                              const float* __restrict__ W2, const float* __restrict__ W3,
                              _Float16* __restrict__ T0, _Float16* __restrict__ T1,
                              _Float16* __restrict__ T2, _Float16* __restrict__ T3) {
  const float* W; _Float16* T;
  switch (blockIdx.z) {
    case 0: W = W0; T = T0; break;
    case 1: W = W1; T = T1; break;
    case 2: W = W2; T = T2; break;
    default: W = W3; T = T3; break;
  }
  __shared__ float tile[32][33];
  int tx = threadIdx.x & 31, ty = threadIdx.x >> 5;
  int k0 = blockIdx.x * 32, n0 = blockIdx.y * 32;
#pragma unroll
  for (int i = 0; i < 4; i++) {
    int r = ty + i * 8;
    tile[r][tx] = W[(size_t)(k0 + r) * DD + n0 + tx];
  }
  __syncthreads();
#pragma unroll
  for (int i = 0; i < 4; i++) {
    int r = ty + i * 8;
    T[(size_t)(n0 + r) * DD + k0 + tx] = (_Float16)tile[tx][r];
  }
}

// ---------------- fp32 -> f16 convert ----------------
__global__ void cvt_kernel(const float* __restrict__ in, _Float16* __restrict__ out, int n4) {
  int i = blockIdx.x * 256 + threadIdx.x;
  if (i >= n4) return;
  float4 v = ((const float4*)in)[i];
  half4v h = {(_Float16)v.x, (_Float16)v.y, (_Float16)v.z, (_Float16)v.w};
  *(half4v*)(out + 4 * (size_t)i) = h;
}

// ---------------- shared 128x128 GEMM core (global_load_lds staging) ----------
// LDS tiles: unpadded [128 rows][32 f16] = 8 KB; slot s (0..511) -> row s>>2,
// 16B chunk s&3, LDS byte s*16 (matches wave-uniform-base + lane*16).
__device__ __forceinline__ void gemm_core(const _Float16* __restrict__ A, size_t lda,
                                          const _Float16* __restrict__ B, size_t ldb,
                                          int kIters, _Float16* As, _Float16* Bs,
                                          int tid, floatx4 acc[4][4]) {
  int lane = tid & 63, w = tid >> 6;
  int l15 = lane & 15, quad = lane >> 4;
  int wm = (w >> 1) * 64, wn = (w & 1) * 64;
  const char* gA0 = (const char*)(A + (size_t)(tid >> 2) * lda + (tid & 3) * 8);
  const char* gA1 = (const char*)(A + ((size_t)(tid >> 2) + 64) * lda + (tid & 3) * 8);
  const char* gB0 = (const char*)(B + (size_t)(tid >> 2) * ldb + (tid & 3) * 8);
  const char* gB1 = (const char*)(B + ((size_t)(tid >> 2) + 64) * ldb + (tid & 3) * 8);
  _Float16* lA0 = As + w * 512; _Float16* lA1 = As + 2048 + w * 512;
  _Float16* lB0 = Bs + w * 512; _Float16* lB1 = Bs + 2048 + w * 512;
  for (int kk = 0; kk < kIters; kk++) {
    __syncthreads();
    size_t off = (size_t)kk * 64;   // 32 f16 columns per iter
    gl_lds16(gA0 + off, lA0);
    gl_lds16(gA1 + off, lA1);
    gl_lds16(gB0 + off, lB0);
    gl_lds16(gB1 + off, lB1);
    __syncthreads();
    half8 a[4];
#pragma unroll
    for (int mi = 0; mi < 4; mi++) a[mi] = *(const half8*)&As[(wm + mi * 16 + l15) * 32 + quad * 8];
#pragma unroll
    for (int ni = 0; ni < 4; ni++) {
      half8 b8 = *(const half8*)&Bs[(wn + ni * 16 + l15) * 32 + quad * 8];
#pragma unroll
      for (int mi = 0; mi < 4; mi++)
        acc[mi][ni] = __builtin_amdgcn_mfma_f32_16x16x32_f16(a[mi], b8, acc[mi][ni], 0, 0, 0);
    }
  }
}

// ---------------- generic single-B GEMM ----------------
template <bool OUTF32>
__launch_bounds__(256, 2)
__global__ void gemm_f16_kernel(const _Float16* __restrict__ A, size_t lda, size_t aoffz,
                                const _Float16* __restrict__ B, size_t ldb, size_t boffz,
                                int kIters, const float* __restrict__ bias, float scale,
                                void* __restrict__ C, size_t ldc, size_t coffz) {
  __shared__ __align__(16) _Float16 As[4096];
  __shared__ __align__(16) _Float16 Bs[4096];
  int tid = threadIdx.x;
  const _Float16* Ab = A + aoffz * blockIdx.z + (size_t)(blockIdx.y * 128) * lda;
  const _Float16* Bb = B + boffz * blockIdx.z + (size_t)(blockIdx.x * 128) * ldb;
  floatx4 acc[4][4];
  floatx4 zero = {0.f, 0.f, 0.f, 0.f};
#pragma unroll
  for (int a = 0; a < 4; a++)
#pragma unroll
    for (int b = 0; b < 4; b++) acc[a][b] = zero;
  gemm_core(Ab, lda, Bb, ldb, kIters, As, Bs, tid, acc);
  int lane = tid & 63, w = tid >> 6;
  int l15 = lane & 15, quad = lane >> 4;
  int wm = (w >> 1) * 64, wn = (w & 1) * 64;
#pragma unroll
  for (int mi = 0; mi < 4; mi++)
#pragma unroll
    for (int ni = 0; ni < 4; ni++) {
      int colg = blockIdx.x * 128 + wn + ni * 16 + l15;
      float bv = bias ? bias[colg] : 0.f;
#pragma unroll
      for (int r = 0; r < 4; r++) {
        int rowg = blockIdx.y * 128 + wm + mi * 16 + quad * 4 + r;
        float v = (acc[mi][ni][r] + bv) * scale;
        size_t idx = coffz * blockIdx.z + (size_t)rowg * ldc + colg;
        if (OUTF32) ((float*)C)[idx] = v;
        else ((_Float16*)C)[idx] = (_Float16)v;
      }
    }
}

// ---------------- fused K/V projection GEMM ----------------
__launch_bounds__(256, 2)
__global__ void gemm_kv_kernel(const _Float16* __restrict__ A,
                               const _Float16* __restrict__ WkT, const _Float16* __restrict__ WvT,
                               const float* __restrict__ bk, const float* __restrict__ bv,
                               _Float16* __restrict__ K, _Float16* __restrict__ Vt) {
  __shared__ __align__(16) _Float16 As[4096];
  __shared__ __align__(16) _Float16 Bk[4096];
  __shared__ __align__(16) _Float16 Bv[4096];
  int tid = threadIdx.x;
  int lane = tid & 63, w = tid >> 6;
  int l15 = lane & 15, quad = lane >> 4;
  int wm = (w >> 1) * 64, wn = (w & 1) * 64;
  int m0 = blockIdx.y * 128, n0 = blockIdx.x * 128;
  floatx4 accK[4][4], accV[4][4];
  floatx4 zero = {0.f, 0.f, 0.f, 0.f};
#pragma unroll
  for (int a = 0; a < 4; a++)
#pragma unroll
    for (int b = 0; b < 4; b++) { accK[a][b] = zero; accV[a][b] = zero; }
  const char* gA0 = (const char*)(A + ((size_t)m0 + (tid >> 2)) * 1024 + (tid & 3) * 8);
  const char* gA1 = gA0 + 64 * 1024 * 2;
  const char* gK0 = (const char*)(WkT + ((size_t)n0 + (tid >> 2)) * 1024 + (tid & 3) * 8);
  const char* gK1 = gK0 + 64 * 1024 * 2;
  const char* gV0 = (const char*)(WvT + ((size_t)n0 + (tid >> 2)) * 1024 + (tid & 3) * 8);
  const char* gV1 = gV0 + 64 * 1024 * 2;
  _Float16* lA0 = As + w * 512; _Float16* lA1 = As + 2048 + w * 512;
  _Float16* lK0 = Bk + w * 512; _Float16* lK1 = Bk + 2048 + w * 512;
  _Float16* lV0 = Bv + w * 512; _Float16* lV1 = Bv + 2048 + w * 512;
  for (int kk = 0; kk < 32; kk++) {
    __syncthreads();
    size_t off = (size_t)kk * 64;
    gl_lds16(gA0 + off, lA0); gl_lds16(gA1 + off, lA1);
    gl_lds16(gK0 + off, lK0); gl_lds16(gK1 + off, lK1);
    gl_lds16(gV0 + off, lV0); gl_lds16(gV1 + off, lV1);
    __syncthreads();
    half8 a[4];
#pragma unroll
    for (int mi = 0; mi < 4; mi++) a[mi] = *(const half8*)&As[(wm + mi * 16 + l15) * 32 + quad * 8];
#pragma unroll
    for (int ni = 0; ni < 4; ni++) {
      half8 k8 = *(const half8*)&Bk[(wn + ni * 16 + l15) * 32 + quad * 8];
      half8 v8 = *(const half8*)&Bv[(wn + ni * 16 + l15) * 32 + quad * 8];
#pragma unroll
      for (int mi = 0; mi < 4; mi++) {
        accK[mi][ni] = __builtin_amdgcn_mfma_f32_16x16x32_f16(a[mi], k8, accK[mi][ni], 0, 0, 0);
        accV[mi][ni] = __builtin_amdgcn_mfma_f32_16x16x32_f16(a[mi], v8, accV[mi][ni], 0, 0, 0);
      }
    }
  }
#pragma unroll
  for (int mi = 0; mi < 4; mi++)
#pragma unroll
    for (int ni = 0; ni < 4; ni++) {
      int col = n0 + wn + ni * 16 + l15;
      float bkv = bk[col], bvv = bv[col];
#pragma unroll
      for (int r = 0; r < 4; r++) {
        int row = m0 + wm + mi * 16 + quad * 4 + r;
        K[(size_t)row * 1024 + col] = (_Float16)(accK[mi][ni][r] + bkv);
        Vt[(size_t)col * TALL + row] = (_Float16)(accV[mi][ni][r] + bvv);
      }
    }
}

// ---------------- softmax stats: m, Z_d -> c-table ----------------
// grid 1024 (= h*256+q), block 256. Each thread covers 64 contiguous keys
// (all in frame f = tid>>2). c_f = 256 * sum_d [f%d==0] w_d / Z_d.
__global__ void stats_kernel(const _Float16* __restrict__ S, const float* __restrict__ dil_w,
                             float* __restrict__ m_tab, float* __restrict__ c_tab) {
  int r = blockIdx.x;
  const _Float16* row = S + (size_t)r * TALL;
  int tid = threadIdx.x;
  half8 v[8];
  float mloc = -1e30f;
#pragma unroll
  for (int i = 0; i < 8; i++) {
    v[i] = *(const half8*)&row[tid * 64 + i * 8];
#pragma unroll
    for (int j = 0; j < 8; j++) mloc = fmaxf(mloc, (float)v[i][j]);
  }
  __shared__ float sred[256];
  __shared__ float Z[4];
  sred[tid] = mloc;
  __syncthreads();
  for (int sft = 128; sft >= 1; sft >>= 1) {
    if (tid < sft) sred[tid] = fmaxf(sred[tid], sred[tid + sft]);
    __syncthreads();
  }
  float m = sred[0];
  if (tid < 4) Z[tid] = 0.f;
  __syncthreads();
  float es = 0.f;
#pragma unroll
  for (int i = 0; i < 8; i++)
#pragma unroll
    for (int j = 0; j < 8; j++) es += __expf((float)v[i][j] - m);
  // reduce 4 threads of the same frame via shuffles
  float fs = es;
  fs += __shfl_xor(fs, 1, 64);
  fs += __shfl_xor(fs, 2, 64);
  int f = tid >> 2;
  if ((tid & 3) == 0) {
    atomicAdd(&Z[0], fs);
    if ((f & 3) == 0) atomicAdd(&Z[1], fs);
    if ((f & 7) == 0) atomicAdd(&Z[2], fs);
    if ((f & 15) == 0) atomicAdd(&Z[3], fs);
  }
  __syncthreads();
  if (tid < 64) {
    float w0 = dil_w[0], w1 = dil_w[1], w2 = dil_w[2], w3 = dil_w[3];
    float wmx = fmaxf(fmaxf(w0, w1), fmaxf(w2, w3));
    float e0 = __expf(w0 - wmx), e1 = __expf(w1 - wmx), e2 = __expf(w2 - wmx), e3 = __expf(w3 - wmx);
    float wsum = e0 + e1 + e2 + e3;
    float c = (e0 / wsum) / Z[0];
    if ((tid & 3) == 0) c += (e1 / wsum) / Z[1];
    if ((tid & 7) == 0) c += (e2 / wsum) / Z[2];
    if ((tid & 15) == 0) c += (e3 / wsum) / Z[3];
    c_tab[r * 64 + tid] = c * 256.0f;   // x256 keeps P in f16 normal range; /256 in reduce
  }
  if (tid == 0) m_tab[r] = m;
}

// ---------------- P write (in place over S) ----------------
__global__ void pwrite_kernel(_Float16* __restrict__ S, const float* __restrict__ m_tab,
                              const float* __restrict__ c_tab) {
  size_t e = ((size_t)blockIdx.x * 256 + threadIdx.x) * 8;
  int r = (int)(e >> 14);
  int f = (int)((e & 16383) >> 8);
  float m = m_tab[r];
  float c = c_tab[r * 64 + f];
  half8 v = *(half8*)&S[e];
  half8 o;
#pragma unroll
  for (int j = 0; j < 8; j++) o[j] = (_Float16)(__expf((float)v[j] - m) * c);
  *(half8*)&S[e] = o;
}

// ---------------- PV GEMM, split-K=16 ----------------
// grid (2 ntile, 2 mtile, 64 = h*16+split)
__launch_bounds__(256, 2)
__global__ void gemm_pv_kernel(const _Float16* __restrict__ P, const _Float16* __restrict__ Vt,
                               float* __restrict__ part) {
  __shared__ __align__(16) _Float16 As[4096];
  __shared__ __align__(16) _Float16 Bs[4096];
  int tid = threadIdx.x;
  int h = blockIdx.z >> 4, sp = blockIdx.z & 15;
  const _Float16* Ab = P + (size_t)h * 4194304 + (size_t)(blockIdx.y * 128) * TALL + sp * 1024;
  const _Float16* Bb = Vt + (size_t)(h * 256 + blockIdx.x * 128) * TALL + sp * 1024;
  floatx4 acc[4][4];
  floatx4 zero = {0.f, 0.f, 0.f, 0.f};
#pragma unroll
  for (int a = 0; a < 4; a++)
#pragma unroll
    for (int b = 0; b < 4; b++) acc[a][b] = zero;
  gemm_core(Ab, TALL, Bb, TALL, 32, As, Bs, tid, acc);
  int lane = tid & 63, w = tid >> 6;
  int l15 = lane & 15, quad = lane >> 4;
  int wm = (w >> 1) * 64, wn = (w & 1) * 64;
#pragma unroll
  for (int mi = 0; mi < 4; mi++)
#pragma unroll
    for (int ni = 0; ni < 4; ni++) {
      int featg = h * 256 + blockIdx.x * 128 + wn + ni * 16 + l15;
#pragma unroll
      for (int r = 0; r < 4; r++) {
        int q = blockIdx.y * 128 + wm + mi * 16 + quad * 4 + r;
        part[((size_t)(sp * 256 + q)) * 1024 + featg] = acc[mi][ni][r];
      }
    }
}

// ---------------- split-K reduce -> comb f16 ----------------
__global__ void reduce_kernel(const float* __restrict__ part, _Float16* __restrict__ comb) {
  int q = blockIdx.x;
  int f4 = threadIdx.x * 4;
  float4 s = {0.f, 0.f, 0.f, 0.f};
  for (int sp = 0; sp < 16; sp++) {
    float4 p = *(const float4*)&part[((size_t)(sp * 256 + q)) * 1024 + f4];
    s.x += p.x; s.y += p.y; s.z += p.z; s.w += p.w;
  }
  const float inv = 1.f / 256.f;
  half4v o = {(_Float16)(s.x * inv), (_Float16)(s.y * inv), (_Float16)(s.z * inv), (_Float16)(s.w * inv)};
  *(half4v*)&comb[(size_t)q * 1024 + f4] = o;
}

// ---------------- residual + layernorm ----------------
__global__ void ln_kernel(const float* __restrict__ x, const float* __restrict__ cproj,
                          const float* __restrict__ gamma, const float* __restrict__ beta,
                          float* __restrict__ out) {
  int b = blockIdx.x, t = threadIdx.x;
  __shared__ float red[8];
  float y[4];
  float sum = 0.f, sq = 0.f;
#pragma unroll
  for (int i = 0; i < 4; i++) {
    int j = t + i * 256;
    y[i] = x[(size_t)b * 1024 + j] + cproj[(size_t)b * 1024 + j];
    sum += y[i];
    sq += y[i] * y[i];
  }
#pragma unroll
  for (int off = 1; off < 64; off <<= 1) {
    sum += __shfl_xor(sum, off, 64);
    sq += __shfl_xor(sq, off, 64);
  }
  int w = t >> 6, lane = t & 63;
  if (lane == 0) { red[w] = sum; red[4 + w] = sq; }
  __syncthreads();
  sum = red[0] + red[1] + red[2] + red[3];
  sq = red[4] + red[5] + red[6] + red[7];
  float mu = sum * (1.f / 1024.f);
  float var = sq * (1.f / 1024.f) - mu * mu;
  float inv = rsqrtf(var + 1e-5f);
#pragma unroll
  for (int i = 0; i < 4; i++) {
    int j = t + i * 256;
    out[(size_t)b * 1024 + j] = (y[i] - mu) * inv * gamma[j] + beta[j];
  }
}

// ---------------- host launch ----------------
extern "C" void kernel_launch(void* const* d_in, const int* in_sizes, int n_in,
                              void* d_out, int out_size, void* d_ws, size_t ws_size,
                              hipStream_t stream) {
  const float* x     = (const float*)d_in[0];
  const float* hist  = (const float*)d_in[1];
  const float* Wq    = (const float*)d_in[2];
  const float* bq    = (const float*)d_in[3];
  const float* Wk    = (const float*)d_in[4];
  const float* bk    = (const float*)d_in[5];
  const float* Wv    = (const float*)d_in[6];
  const float* bv    = (const float*)d_in[7];
  const float* Wo    = (const float*)d_in[8];
  const float* bo    = (const float*)d_in[9];
  const float* dil_w = (const float*)d_in[10];
  const float* gamma = (const float*)d_in[11];
  const float* beta  = (const float*)d_in[12];
  char* ws = (char*)d_ws;

  _Float16* WqT   = (_Float16*)(ws + OFF_WQT);
  _Float16* WkT   = (_Float16*)(ws + OFF_WKT);
  _Float16* WvT   = (_Float16*)(ws + OFF_WVT);
  _Float16* WoT   = (_Float16*)(ws + OFF_WOT);
  _Float16* xb    = (_Float16*)(ws + OFF_XB);
  _Float16* Qs    = (_Float16*)(ws + OFF_QS);
  _Float16* histb = (_Float16*)(ws + OFF_HB);
  _Float16* Sb    = (_Float16*)(ws + OFF_S);    // aliases histb (free after KV gemm)
  _Float16* Kb    = (_Float16*)(ws + OFF_KB);
  _Float16* Vtb   = (_Float16*)(ws + OFF_VT);
  float* part     = (float*)(ws + OFF_PART);
  float* m_tab    = (float*)(ws + OFF_MT);
  float* c_tab    = (float*)(ws + OFF_CT);
  _Float16* comb  = (_Float16*)(ws + OFF_CB);
  float* cproj    = (float*)(ws + OFF_CP);

  // 1) weights -> transposed f16
  wtrans_kernel<<<dim3(32, 32, 4), 256, 0, stream>>>(Wq, Wk, Wv, Wo, WqT, WkT, WvT, WoT);
  // 2) inputs -> f16
  cvt_kernel<<<dim3(16384), 256, 0, stream>>>(hist, histb, 16777216 / 4);
  cvt_kernel<<<dim3(256), 256, 0, stream>>>(x, xb, 262144 / 4);
  // 3) Q projection (scale 1/sqrt(HD) folded)
  gemm_f16_kernel<false><<<dim3(8, 2, 1), 256, 0, stream>>>(
      xb, 1024, 0, WqT, 1024, 0, 32, bq, 0.0625f, (void*)Qs, 1024, 0);
  // 4) fused K / V(t) projection
  gemm_kv_kernel<<<dim3(8, 128), 256, 0, stream>>>(histb, WkT, WvT, bk, bv, Kb, Vtb);
  // 5) S = Q @ K^T per head (f16, overwrites histb region)
  gemm_f16_kernel<false><<<dim3(128, 2, 4), 256, 0, stream>>>(
      Qs, 1024, 256, Kb, 1024, 256, 8, nullptr, 1.0f, (void*)Sb, TALL, 4194304);
  // 6) softmax stats (global max; per-dilation Z; merged frame weights)
  stats_kernel<<<dim3(1024), 256, 0, stream>>>(Sb, dil_w, m_tab, c_tab);
  // 7) P = exp(S - m) * c_frame * 256 (in place)
  pwrite_kernel<<<dim3(8192), 256, 0, stream>>>(Sb, m_tab, c_tab);
  // 8) combined partials = P @ V (split-K 16)
  gemm_pv_kernel<<<dim3(2, 2, 64), 256, 0, stream>>>(Sb, Vtb, part);
  // 9) reduce partials -> comb f16 (/256)
  reduce_kernel<<<dim3(256), 256, 0, stream>>>(part, comb);
  // 10) output projection (+bo) -> f32
  gemm_f16_kernel<true><<<dim3(8, 2, 1), 256, 0, stream>>>(
      comb, 1024, 0, WoT, 1024, 0, 32, bo, 1.0f, (void*)cproj, 1024, 0);
  // 11) residual + layernorm
  ln_kernel<<<dim3(256), 256, 0, stream>>>(x, cproj, gamma, beta, (float*)d_out);
}

// Round 3
// 327.417 us; speedup vs baseline: 1.2503x; 1.0335x over previous
//
#include <hip/hip_runtime.h>

// TemporalDilatedAttention on gfx950 — round 3
// vs R2: XOR-swizzled LDS tiles (kills 8-way ds_read_b128 conflicts while
// keeping global_load_lds's lane*16 contiguous dest), fused softmax
// (stats+pwrite one pass), PV split-K 32 (2 blocks/CU), out-proj split-K 4
// with reduce fused into layernorm, merged cvt, vectorized Vt store.

#define DD    1024
#define TALL  16384

typedef _Float16 half8  __attribute__((ext_vector_type(8)));
typedef _Float16 half4v __attribute__((ext_vector_type(4)));
typedef float    floatx4 __attribute__((ext_vector_type(4)));
typedef unsigned int u32;

// ---------------- workspace layout (bytes) ----------------
static const size_t OFF_WQT = 0;          // 2 MB
static const size_t OFF_WKT = 2097152;
static const size_t OFF_WVT = 4194304;
static const size_t OFF_WOT = 6291456;
static const size_t OFF_XB  = 8388608;    // 0.5 MB
static const size_t OFF_QS  = 8912896;    // 0.5 MB
static const size_t OFF_HB  = 16777216;   // 32 MB hist f16; S/P aliases after KV gemm
static const size_t OFF_S   = OFF_HB;
static const size_t OFF_KB  = 50331648;   // 32 MB K; PV partials alias after S gemm
static const size_t OFF_PVP = OFF_KB;     // 32 x 256 x 1024 f32 = 32 MB
static const size_t OFF_VT  = 83886080;   // 32 MB (V transposed [feat][t])
static const size_t OFF_OPP = 117440512;  // out-proj partials 4 x 256 x 1024 f32 = 4 MB
static const size_t OFF_CB  = 134483968;  // comb 256x1024 f16 = 0.5 MB

// ---------------- async global->LDS, 16B per lane ----------------
__device__ __forceinline__ void gl_lds16(const void* g, void* l) {
  __builtin_amdgcn_global_load_lds((const __attribute__((address_space(1))) u32*)g,
                                   (__attribute__((address_space(3))) u32*)l, 16, 0, 0);
}

// ---------------- weight transpose + convert ----------------
__global__ void wtrans_kernel(const float* __restrict__ W0, const float* __restrict__ W1,
                              const float* __restrict__ W2, const float* __restrict__ W3,
                              _Float16* __restrict__ T0, _Float16* __restrict__ T1,
                              _Float16* __restrict__ T2, _Float16* __restrict__ T3) {
  const float* W; _Float16* T;
  switch (blockIdx.z) {
    case 0: W = W0; T = T0; break;
    case 1: W = W1; T = T1; break;
    case 2: W = W2; T = T2; break;
    default: W = W3; T = T3; break;
  }
  __shared__ float tile[32][33];
  int tx = threadIdx.x & 31, ty = threadIdx.x >> 5;
  int k0 = blockIdx.x * 32, n0 = blockIdx.y * 32;
#pragma unroll
  for (int i = 0; i < 4; i++) {
    int r = ty + i * 8;
    tile[r][tx] = W[(size_t)(k0 + r) * DD + n0 + tx];
  }
  __syncthreads();
#pragma unroll
  for (int i = 0; i < 4; i++) {
    int r = ty + i * 8;
    T[(size_t)(n0 + r) * DD + k0 + tx] = (_Float16)tile[tx][r];
  }
}

// ---------------- fp32 -> f16 convert (hist + x in one launch) ------------
__global__ void cvt2_kernel(const float* __restrict__ a, _Float16* __restrict__ oa, int na4,
                            const float* __restrict__ b, _Float16* __restrict__ ob, int nb4) {
  int i = blockIdx.x * 256 + threadIdx.x;
  const float* src; _Float16* dst;
  if (i < na4) { src = a; dst = oa; }
  else { i -= na4; if (i >= nb4) return; src = b; dst = ob; }
  float4 v = ((const float4*)src)[i];
  half4v h = {(_Float16)v.x, (_Float16)v.y, (_Float16)v.z, (_Float16)v.w};
  *(half4v*)(dst + 4 * (size_t)i) = h;
}

// ---------------- shared 128x128 GEMM core, XOR-swizzled LDS --------------
// Physical LDS: [128 rows][32 f16]; slot s -> byte s*16 (global_load_lds dest
// is wave-uniform base + lane*16, fixed). Logical chunk c of row r is stored
// at physical chunk c ^ ((r>>1)&3): staging picks the matching GLOBAL chunk
// per lane; fragment reads apply the same XOR -> 2-way banks (free, m136).
__device__ __forceinline__ void gemm_core(const _Float16* __restrict__ A, size_t lda,
                                          const _Float16* __restrict__ B, size_t ldb,
                                          int kIters, _Float16* As, _Float16* Bs,
                                          int tid, floatx4 acc[4][4]) {
  int lane = tid & 63, w = tid >> 6;
  int l15 = lane & 15, quad = lane >> 4;
  int wm = (w >> 1) * 64, wn = (w & 1) * 64;
  int swz = ((tid & 3) ^ ((tid >> 3) & 3)) * 8;            // staging-side XOR (f16 elems)
  int pch = (quad ^ ((l15 >> 1) & 3)) * 8;                 // read-side XOR (f16 elems)
  const char* gA0 = (const char*)(A + (size_t)(tid >> 2) * lda + swz);
  const char* gA1 = (const char*)(A + ((size_t)(tid >> 2) + 64) * lda + swz);
  const char* gB0 = (const char*)(B + (size_t)(tid >> 2) * ldb + swz);
  const char* gB1 = (const char*)(B + ((size_t)(tid >> 2) + 64) * ldb + swz);
  _Float16* lA0 = As + w * 512; _Float16* lA1 = As + 2048 + w * 512;
  _Float16* lB0 = Bs + w * 512; _Float16* lB1 = Bs + 2048 + w * 512;
  for (int kk = 0; kk < kIters; kk++) {
    __syncthreads();
    size_t off = (size_t)kk * 64;   // 32 f16 per iter
    gl_lds16(gA0 + off, lA0);
    gl_lds16(gA1 + off, lA1);
    gl_lds16(gB0 + off, lB0);
    gl_lds16(gB1 + off, lB1);
    __syncthreads();
    half8 a[4];
#pragma unroll
    for (int mi = 0; mi < 4; mi++) a[mi] = *(const half8*)&As[(wm + mi * 16 + l15) * 32 + pch];
#pragma unroll
    for (int ni = 0; ni < 4; ni++) {
      half8 b8 = *(const half8*)&Bs[(wn + ni * 16 + l15) * 32 + pch];
#pragma unroll
      for (int mi = 0; mi < 4; mi++)
        acc[mi][ni] = __builtin_amdgcn_mfma_f32_16x16x32_f16(a[mi], b8, acc[mi][ni], 0, 0, 0);
    }
  }
}

// ---------------- generic single-B GEMM (z-batched / split-K via offsets) --
template <bool OUTF32>
__launch_bounds__(256, 3)
__global__ void gemm_f16_kernel(const _Float16* __restrict__ A, size_t lda, size_t aoffz,
                                const _Float16* __restrict__ B, size_t ldb, size_t boffz,
                                int kIters, const float* __restrict__ bias, float scale,
                                void* __restrict__ C, size_t ldc, size_t coffz) {
  __shared__ __align__(16) _Float16 As[4096];
  __shared__ __align__(16) _Float16 Bs[4096];
  int tid = threadIdx.x;
  const _Float16* Ab = A + aoffz * blockIdx.z + (size_t)(blockIdx.y * 128) * lda;
  const _Float16* Bb = B + boffz * blockIdx.z + (size_t)(blockIdx.x * 128) * ldb;
  floatx4 acc[4][4];
  floatx4 zero = {0.f, 0.f, 0.f, 0.f};
#pragma unroll
  for (int a = 0; a < 4; a++)
#pragma unroll
    for (int b = 0; b < 4; b++) acc[a][b] = zero;
  gemm_core(Ab, lda, Bb, ldb, kIters, As, Bs, tid, acc);
  int lane = tid & 63, w = tid >> 6;
  int l15 = lane & 15, quad = lane >> 4;
  int wm = (w >> 1) * 64, wn = (w & 1) * 64;
#pragma unroll
  for (int mi = 0; mi < 4; mi++)
#pragma unroll
    for (int ni = 0; ni < 4; ni++) {
      int colg = blockIdx.x * 128 + wn + ni * 16 + l15;
      float bv = bias ? bias[colg] : 0.f;
#pragma unroll
      for (int r = 0; r < 4; r++) {
        int rowg = blockIdx.y * 128 + wm + mi * 16 + quad * 4 + r;
        float v = (acc[mi][ni][r] + bv) * scale;
        size_t idx = coffz * blockIdx.z + (size_t)rowg * ldc + colg;
        if (OUTF32) ((float*)C)[idx] = v;
        else ((_Float16*)C)[idx] = (_Float16)v;
      }
    }
}

// ---------------- fused K/V projection GEMM ----------------
__launch_bounds__(256, 2)
__global__ void gemm_kv_kernel(const _Float16* __restrict__ A,
                               const _Float16* __restrict__ WkT, const _Float16* __restrict__ WvT,
                               const float* __restrict__ bk, const float* __restrict__ bv,
                               _Float16* __restrict__ K, _Float16* __restrict__ Vt) {
  __shared__ __align__(16) _Float16 As[4096];
  __shared__ __align__(16) _Float16 Bk[4096];
  __shared__ __align__(16) _Float16 Bv[4096];
  int tid = threadIdx.x;
  int lane = tid & 63, w = tid >> 6;
  int l15 = lane & 15, quad = lane >> 4;
  int wm = (w >> 1) * 64, wn = (w & 1) * 64;
  int m0 = blockIdx.y * 128, n0 = blockIdx.x * 128;
  int swz = ((tid & 3) ^ ((tid >> 3) & 3)) * 8;
  int pch = (quad ^ ((l15 >> 1) & 3)) * 8;
  floatx4 accK[4][4], accV[4][4];
  floatx4 zero = {0.f, 0.f, 0.f, 0.f};
#pragma unroll
  for (int a = 0; a < 4; a++)
#pragma unroll
    for (int b = 0; b < 4; b++) { accK[a][b] = zero; accV[a][b] = zero; }
  const char* gA0 = (const char*)(A + ((size_t)m0 + (tid >> 2)) * 1024 + swz);
  const char* gA1 = gA0 + 64 * 1024 * 2;
  const char* gK0 = (const char*)(WkT + ((size_t)n0 + (tid >> 2)) * 1024 + swz);
  const char* gK1 = gK0 + 64 * 1024 * 2;
  const char* gV0 = (const char*)(WvT + ((size_t)n0 + (tid >> 2)) * 1024 + swz);
  const char* gV1 = gV0 + 64 * 1024 * 2;
  _Float16* lA0 = As + w * 512; _Float16* lA1 = As + 2048 + w * 512;
  _Float16* lK0 = Bk + w * 512; _Float16* lK1 = Bk + 2048 + w * 512;
  _Float16* lV0 = Bv + w * 512; _Float16* lV1 = Bv + 2048 + w * 512;
  for (int kk = 0; kk < 32; kk++) {
    __syncthreads();
    size_t off = (size_t)kk * 64;
    gl_lds16(gA0 + off, lA0); gl_lds16(gA1 + off, lA1);
    gl_lds16(gK0 + off, lK0); gl_lds16(gK1 + off, lK1);
    gl_lds16(gV0 + off, lV0); gl_lds16(gV1 + off, lV1);
    __syncthreads();
    half8 a[4];
#pragma unroll
    for (int mi = 0; mi < 4; mi++) a[mi] = *(const half8*)&As[(wm + mi * 16 + l15) * 32 + pch];
#pragma unroll
    for (int ni = 0; ni < 4; ni++) {
      half8 k8 = *(const half8*)&Bk[(wn + ni * 16 + l15) * 32 + pch];
      half8 v8 = *(const half8*)&Bv[(wn + ni * 16 + l15) * 32 + pch];
#pragma unroll
      for (int mi = 0; mi < 4; mi++) {
        accK[mi][ni] = __builtin_amdgcn_mfma_f32_16x16x32_f16(a[mi], k8, accK[mi][ni], 0, 0, 0);
        accV[mi][ni] = __builtin_amdgcn_mfma_f32_16x16x32_f16(a[mi], v8, accV[mi][ni], 0, 0, 0);
      }
    }
  }
#pragma unroll
  for (int mi = 0; mi < 4; mi++)
#pragma unroll
    for (int ni = 0; ni < 4; ni++) {
      int col = n0 + wn + ni * 16 + l15;
      float bkv = bk[col], bvv = bv[col];
      int row0 = m0 + wm + mi * 16 + quad * 4;
#pragma unroll
      for (int r = 0; r < 4; r++)
        K[(size_t)(row0 + r) * 1024 + col] = (_Float16)(accK[mi][ni][r] + bkv);
      half4v vv = {(_Float16)(accV[mi][ni][0] + bvv), (_Float16)(accV[mi][ni][1] + bvv),
                   (_Float16)(accV[mi][ni][2] + bvv), (_Float16)(accV[mi][ni][3] + bvv)};
      *(half4v*)&Vt[(size_t)col * TALL + row0] = vv;
    }
}

// ---------------- fused softmax: max, per-dilation Z, P write (one pass) ---
// grid 1024 rows (h*256+q), block 256. Row (16384 f16 = 32 KB) held in regs.
// chunk (i,tid) = keys [ (i*256+tid)*8 .. +7 ], all inside frame i*8+(tid>>5).
__global__ void softmax_kernel(_Float16* __restrict__ S, const float* __restrict__ dil_w) {
  int r = blockIdx.x, tid = threadIdx.x;
  _Float16* row = S + (size_t)r * TALL;
  int lane = tid & 63, w = tid >> 6;
  half8 v[8];
  float mloc = -1e30f;
#pragma unroll
  for (int i = 0; i < 8; i++) {
    v[i] = *(const half8*)&row[((size_t)i * 256 + tid) * 8];
#pragma unroll
    for (int j = 0; j < 8; j++) mloc = fmaxf(mloc, (float)v[i][j]);
  }
  __shared__ float wmax[4];
  __shared__ float Zf[64];
  __shared__ float Zd[4];
  __shared__ float cf[64];
#pragma unroll
  for (int off = 1; off <= 32; off <<= 1) mloc = fmaxf(mloc, __shfl_xor(mloc, off, 64));
  if (lane == 0) wmax[w] = mloc;
  __syncthreads();
  float m = fmaxf(fmaxf(wmax[0], wmax[1]), fmaxf(wmax[2], wmax[3]));
  float es[8];
#pragma unroll
  for (int i = 0; i < 8; i++) {
    float s = 0.f;
#pragma unroll
    for (int j = 0; j < 8; j++) s += __expf((float)v[i][j] - m);
#pragma unroll
    for (int off = 1; off <= 16; off <<= 1) s += __shfl_xor(s, off, 64);  // 32-lane halves
    es[i] = s;
  }
  if ((lane & 31) == 0) {
    int half = tid >> 5;               // 0..7, unique per half-wave
#pragma unroll
    for (int i = 0; i < 8; i++) Zf[i * 8 + half] = es[i];   // single writer per frame
  }
  __syncthreads();
  if (tid < 4) {
    int step = 1 << (tid + (tid ? 1 : 0));   // d=1,4,8,16 -> step 1,4,8,16
    float z = 0.f;
    for (int f = 0; f < 64; f += step) z += Zf[f];
    Zd[tid] = z;
  }
  __syncthreads();
  if (tid < 64) {
    float w0 = dil_w[0], w1 = dil_w[1], w2 = dil_w[2], w3 = dil_w[3];
    float wmx = fmaxf(fmaxf(w0, w1), fmaxf(w2, w3));
    float e0 = __expf(w0 - wmx), e1 = __expf(w1 - wmx), e2 = __expf(w2 - wmx), e3 = __expf(w3 - wmx);
    float wsum = e0 + e1 + e2 + e3;
    float c = (e0 / wsum) / Zd[0];
    if ((tid & 3) == 0) c += (e1 / wsum) / Zd[1];
    if ((tid & 7) == 0) c += (e2 / wsum) / Zd[2];
    if ((tid & 15) == 0) c += (e3 / wsum) / Zd[3];
    cf[tid] = c * 256.0f;   // x256 keeps P in f16 normal range; /256 in reduce
  }
  __syncthreads();
#pragma unroll
  for (int i = 0; i < 8; i++) {
    float c = cf[i * 8 + (tid >> 5)];
    half8 o;
#pragma unroll
    for (int j = 0; j < 8; j++) o[j] = (_Float16)(__expf((float)v[i][j] - m) * c);
    *(half8*)&row[((size_t)i * 256 + tid) * 8] = o;
  }
}

// ---------------- PV GEMM, split-K=32 ----------------
// grid (2 ntile, 2 mtile, 128 = h*32+split)
__launch_bounds__(256, 3)
__global__ void gemm_pv_kernel(const _Float16* __restrict__ P, const _Float16* __restrict__ Vt,
                               float* __restrict__ part) {
  __shared__ __align__(16) _Float16 As[4096];
  __shared__ __align__(16) _Float16 Bs[4096];
  int tid = threadIdx.x;
  int h = blockIdx.z >> 5, sp = blockIdx.z & 31;
  const _Float16* Ab = P + (size_t)h * 4194304 + (size_t)(blockIdx.y * 128) * TALL + sp * 512;
  const _Float16* Bb = Vt + (size_t)(h * 256 + blockIdx.x * 128) * TALL + sp * 512;
  floatx4 acc[4][4];
  floatx4 zero = {0.f, 0.f, 0.f, 0.f};
#pragma unroll
  for (int a = 0; a < 4; a++)
#pragma unroll
    for (int b = 0; b < 4; b++) acc[a][b] = zero;
  gemm_core(Ab, TALL, Bb, TALL, 16, As, Bs, tid, acc);
  int lane = tid & 63, w = tid >> 6;
  int l15 = lane & 15, quad = lane >> 4;
  int wm = (w >> 1) * 64, wn = (w & 1) * 64;
#pragma unroll
  for (int mi = 0; mi < 4; mi++)
#pragma unroll
    for (int ni = 0; ni < 4; ni++) {
      int featg = h * 256 + blockIdx.x * 128 + wn + ni * 16 + l15;
#pragma unroll
      for (int r = 0; r < 4; r++) {
        int q = blockIdx.y * 128 + wm + mi * 16 + quad * 4 + r;
        part[((size_t)(sp * 256 + q)) * 1024 + featg] = acc[mi][ni][r];
      }
    }
}

// ---------------- split-K reduce -> comb f16 (/256) ----------------
__global__ void reduce_kernel(const float* __restrict__ part, _Float16* __restrict__ comb) {
  int q = blockIdx.x;
  int f4 = threadIdx.x * 4;
  float4 s = {0.f, 0.f, 0.f, 0.f};
  for (int sp = 0; sp < 32; sp++) {
    float4 p = *(const float4*)&part[((size_t)(sp * 256 + q)) * 1024 + f4];
    s.x += p.x; s.y += p.y; s.z += p.z; s.w += p.w;
  }
  const float inv = 1.f / 256.f;
  half4v o = {(_Float16)(s.x * inv), (_Float16)(s.y * inv), (_Float16)(s.z * inv), (_Float16)(s.w * inv)};
  *(half4v*)&comb[(size_t)q * 1024 + f4] = o;
}

// ---------------- out-proj 4-way reduce + bias + residual + layernorm ------
__global__ void ln_kernel(const float* __restrict__ x, const float* __restrict__ part2,
                          const float* __restrict__ bo, const float* __restrict__ gamma,
                          const float* __restrict__ beta, float* __restrict__ out) {
  int b = blockIdx.x, t = threadIdx.x;
  __shared__ float red[8];
  float y[4];
  float sum = 0.f, sq = 0.f;
#pragma unroll
  for (int i = 0; i < 4; i++) {
    int j = t + i * 256;
    float v = x[(size_t)b * 1024 + j] + bo[j];
#pragma unroll
    for (int z = 0; z < 4; z++) v += part2[(size_t)z * 262144 + (size_t)b * 1024 + j];
    y[i] = v;
    sum += v;
    sq += v * v;
  }
#pragma unroll
  for (int off = 1; off < 64; off <<= 1) {
    sum += __shfl_xor(sum, off, 64);
    sq += __shfl_xor(sq, off, 64);
  }
  int w = t >> 6, lane = t & 63;
  if (lane == 0) { red[w] = sum; red[4 + w] = sq; }
  __syncthreads();
  sum = red[0] + red[1] + red[2] + red[3];
  sq = red[4] + red[5] + red[6] + red[7];
  float mu = sum * (1.f / 1024.f);
  float var = sq * (1.f / 1024.f) - mu * mu;
  float inv = rsqrtf(var + 1e-5f);
#pragma unroll
  for (int i = 0; i < 4; i++) {
    int j = t + i * 256;
    out[(size_t)b * 1024 + j] = (y[i] - mu) * inv * gamma[j] + beta[j];
  }
}

// ---------------- host launch ----------------
extern "C" void kernel_launch(void* const* d_in, const int* in_sizes, int n_in,
                              void* d_out, int out_size, void* d_ws, size_t ws_size,
                              hipStream_t stream) {
  const float* x     = (const float*)d_in[0];
  const float* hist  = (const float*)d_in[1];
  const float* Wq    = (const float*)d_in[2];
  const float* bq    = (const float*)d_in[3];
  const float* Wk    = (const float*)d_in[4];
  const float* bk    = (const float*)d_in[5];
  const float* Wv    = (const float*)d_in[6];
  const float* bv    = (const float*)d_in[7];
  const float* Wo    = (const float*)d_in[8];
  const float* bo    = (const float*)d_in[9];
  const float* dil_w = (const float*)d_in[10];
  const float* gamma = (const float*)d_in[11];
  const float* beta  = (const float*)d_in[12];
  char* ws = (char*)d_ws;

  _Float16* WqT   = (_Float16*)(ws + OFF_WQT);
  _Float16* WkT   = (_Float16*)(ws + OFF_WKT);
  _Float16* WvT   = (_Float16*)(ws + OFF_WVT);
  _Float16* WoT   = (_Float16*)(ws + OFF_WOT);
  _Float16* xb    = (_Float16*)(ws + OFF_XB);
  _Float16* Qs    = (_Float16*)(ws + OFF_QS);
  _Float16* histb = (_Float16*)(ws + OFF_HB);
  _Float16* Sb    = (_Float16*)(ws + OFF_S);    // aliases histb
  _Float16* Kb    = (_Float16*)(ws + OFF_KB);
  _Float16* Vtb   = (_Float16*)(ws + OFF_VT);
  float* pvpart   = (float*)(ws + OFF_PVP);     // aliases Kb (free after S gemm)
  float* oppart   = (float*)(ws + OFF_OPP);
  _Float16* comb  = (_Float16*)(ws + OFF_CB);

  // 1) weights -> transposed f16
  wtrans_kernel<<<dim3(32, 32, 4), 256, 0, stream>>>(Wq, Wk, Wv, Wo, WqT, WkT, WvT, WoT);
  // 2) hist + x -> f16 (one launch)
  cvt2_kernel<<<dim3(16640), 256, 0, stream>>>(hist, histb, 4194304, x, xb, 65536);
  // 3) Q projection (scale 1/sqrt(HD) folded)
  gemm_f16_kernel<false><<<dim3(8, 2, 1), 256, 0, stream>>>(
      xb, 1024, 0, WqT, 1024, 0, 32, bq, 0.0625f, (void*)Qs, 1024, 0);
  // 4) fused K / V(t) projection
  gemm_kv_kernel<<<dim3(8, 128), 256, 0, stream>>>(histb, WkT, WvT, bk, bv, Kb, Vtb);
  // 5) S = Q @ K^T per head (f16, overwrites histb region)
  gemm_f16_kernel<false><<<dim3(128, 2, 4), 256, 0, stream>>>(
      Qs, 1024, 256, Kb, 1024, 256, 8, nullptr, 1.0f, (void*)Sb, TALL, 4194304);
  // 6) fused softmax: global max, per-dilation Z, merged frame weights, P in place
  softmax_kernel<<<dim3(1024), 256, 0, stream>>>(Sb, dil_w);
  // 7) combined partials = P @ V (split-K 32; partials alias Kb)
  gemm_pv_kernel<<<dim3(2, 2, 128), 256, 0, stream>>>(Sb, Vtb, pvpart);
  // 8) reduce partials -> comb f16
  reduce_kernel<<<dim3(256), 256, 0, stream>>>(pvpart, comb);
  // 9) output projection, split-K 4 -> f32 partials
  gemm_f16_kernel<true><<<dim3(8, 2, 4), 256, 0, stream>>>(
      comb, 1024, 256, WoT, 1024, 256, 8, nullptr, 1.0f, (void*)oppart, 1024, 262144);
  // 10) 4-way reduce + bo + residual + layernorm
  ln_kernel<<<dim3(256), 256, 0, stream>>>(x, oppart, bo, gamma, beta, (float*)d_out);
}